// Round 1
// baseline (232.400 us; speedup 1.0000x reference)
//
#include <hip/hip_runtime.h>

// Problem constants (fixed by harness setup_inputs):
// B=2, V=5, C=32, H=256, W=320, D=CostNum=4, G=4
#define Bsz 2
#define Vn  5
#define Cn  32
#define Gg  4
#define Hh  256
#define Ww  320
#define Dd  4
#define HWp (Hh*Ww)

// ---------------------------------------------------------------------------
// Setup kernel: per batch, build make_proj(P) for all views, invert ref proj,
// store rot(3x3)+trans(3) of src_proj @ inv(ref_proj) for each src view.
// RT layout: [(b*(Vn-1)+i)*12] = r00 r01 r02 r10 r11 r12 r20 r21 r22 t0 t1 t2
// ---------------------------------------------------------------------------
__global__ void setup_rt(const float* __restrict__ pm, float* __restrict__ RT) {
    int b = threadIdx.x;
    if (b >= Bsz) return;

    float P[Vn][16];
    for (int v = 0; v < Vn; ++v) {
        const float* E = pm + ((b * Vn + v) * 2 + 0) * 16;
        const float* K = pm + ((b * Vn + v) * 2 + 1) * 16;
        // top = K[:3,:3] @ E[:3,:4]
        for (int i = 0; i < 3; ++i)
            for (int j = 0; j < 4; ++j) {
                float s = 0.f;
                for (int k = 0; k < 3; ++k) s += K[i * 4 + k] * E[k * 4 + j];
                P[v][i * 4 + j] = s;
            }
        for (int j = 0; j < 4; ++j) P[v][12 + j] = E[12 + j];
    }

    // Gauss-Jordan inverse of P[0] with partial pivoting (fp32)
    float A[4][8];
    for (int i = 0; i < 4; ++i)
        for (int j = 0; j < 4; ++j) {
            A[i][j] = P[0][i * 4 + j];
            A[i][4 + j] = (i == j) ? 1.f : 0.f;
        }
    for (int col = 0; col < 4; ++col) {
        int piv = col;
        float best = fabsf(A[col][col]);
        for (int r = col + 1; r < 4; ++r) {
            float v = fabsf(A[r][col]);
            if (v > best) { best = v; piv = r; }
        }
        if (piv != col)
            for (int j = 0; j < 8; ++j) {
                float t = A[col][j]; A[col][j] = A[piv][j]; A[piv][j] = t;
            }
        float inv = 1.f / A[col][col];
        for (int j = 0; j < 8; ++j) A[col][j] *= inv;
        for (int r = 0; r < 4; ++r)
            if (r != col) {
                float f = A[r][col];
                for (int j = 0; j < 8; ++j) A[r][j] -= f * A[col][j];
            }
    }
    float inv0[16];
    for (int i = 0; i < 4; ++i)
        for (int j = 0; j < 4; ++j) inv0[i * 4 + j] = A[i][4 + j];

    for (int i2 = 0; i2 < Vn - 1; ++i2) {
        const float* Ps = P[i2 + 1];
        float M[12];
        for (int i = 0; i < 3; ++i)
            for (int j = 0; j < 4; ++j) {
                float s = 0.f;
                for (int k = 0; k < 4; ++k) s += Ps[i * 4 + k] * inv0[k * 4 + j];
                M[i * 4 + j] = s;
            }
        float* o = RT + (b * (Vn - 1) + i2) * 12;
        o[0] = M[0];  o[1] = M[1];  o[2] = M[2];
        o[3] = M[4];  o[4] = M[5];  o[5] = M[6];
        o[6] = M[8];  o[7] = M[9];  o[8] = M[10];
        o[9] = M[3];  o[10] = M[7]; o[11] = M[11];
    }
}

// ---------------------------------------------------------------------------
// Main kernel: one thread per (b, d, pixel). p fastest -> coalesced ref loads,
// wave-uniform d. Per view: warp coords, masked bilinear weights, unrolled
// 32-channel gather+dot into acc[G].
// ---------------------------------------------------------------------------
__global__ __launch_bounds__(256) void getcost_main(
    const float* __restrict__ inv_depth,
    const float* __restrict__ features,
    const float* __restrict__ view_weights,
    const float* __restrict__ confidence,
    const float* __restrict__ sc_interval,
    const float* __restrict__ sc_dmax,
    const float* __restrict__ sc_dmin,
    const float* __restrict__ RT,
    float* __restrict__ out)
{
    int tid = blockIdx.x * blockDim.x + threadIdx.x;
    if (tid >= Bsz * Dd * HWp) return;
    int p  = tid % HWp;
    int bd = tid / HWp;
    int d  = bd % Dd;
    int b  = bd / Dd;
    int h  = p / Ww;
    int w  = p % Ww;

    float dI    = sc_interval[0];
    float dmaxv = sc_dmax[0];
    float dminv = sc_dmin[0];

    float cur  = inv_depth[b * HWp + p];
    float conf = confidence[b * HWp + p];
    float radius0 = (float)(Dd / 2) * dI;
    float radius  = 0.2f * radius0 + (1.0f - conf) * 1.8f * radius0;
    float dmin_   = cur - radius;
    float interval = 2.0f * radius / (float)(Dd - 1);
    float sample = (float)d * interval + dmin_;
    sample = fminf(fmaxf(sample, 0.0f), 1.0f);
    float min_disp = 1.0f / dmaxv;
    float max_disp = 1.0f / dminv;
    float depth = 1.0f / fmaxf(min_disp + (max_disp - min_disp) * sample, 1e-6f);

    // ref feature channels (coalesced: lanes consecutive in p)
    float ref[Cn];
    const float* reff = features + (size_t)b * Cn * HWp + p;
    #pragma unroll
    for (int c = 0; c < Cn; ++c) ref[c] = reff[(size_t)c * HWp];

    float acc[Gg] = {0.f, 0.f, 0.f, 0.f};
    float vw_sum = 1e-8f;
    float xf = (float)w, yf = (float)h;

    #pragma unroll
    for (int i = 0; i < Vn - 1; ++i) {
        const float* rt = RT + (b * (Vn - 1) + i) * 12;
        float rx = rt[0] * xf + rt[1] * yf + rt[2];
        float ry = rt[3] * xf + rt[4] * yf + rt[5];
        float rz = rt[6] * xf + rt[7] * yf + rt[8];
        float wvw = view_weights[((size_t)(b * (Vn - 1) + i)) * HWp + p];
        vw_sum += wvw;

        float ptx = rx * depth + rt[9];
        float pty = ry * depth + rt[10];
        float ptz = rz * depth + rt[11];
        if (ptz == 0.0f) ptz = 1e-8f;
        float px = ptx / ptz, py = pty / ptz;

        float x0 = floorf(px), y0 = floorf(py);
        float wx = px - x0,   wy = py - y0;
        float x1 = x0 + 1.0f, y1 = y0 + 1.0f;
        bool vx0 = (x0 >= 0.f) && (x0 <= (float)(Ww - 1));
        bool vx1 = (x1 >= 0.f) && (x1 <= (float)(Ww - 1));
        bool vy0 = (y0 >= 0.f) && (y0 <= (float)(Hh - 1));
        bool vy1 = (y1 >= 0.f) && (y1 <= (float)(Hh - 1));
        int ix0 = (int)fminf(fmaxf(x0, 0.f), (float)(Ww - 1));
        int ix1 = (int)fminf(fmaxf(x1, 0.f), (float)(Ww - 1));
        int iy0 = (int)fminf(fmaxf(y0, 0.f), (float)(Hh - 1));
        int iy1 = (int)fminf(fmaxf(y1, 0.f), (float)(Hh - 1));
        float w00 = (vx0 && vy0) ? (1.f - wx) * (1.f - wy) : 0.f;
        float w10 = (vx1 && vy0) ? wx * (1.f - wy) : 0.f;
        float w01 = (vx0 && vy1) ? (1.f - wx) * wy : 0.f;
        float w11 = (vx1 && vy1) ? wx * wy : 0.f;
        int o00 = iy0 * Ww + ix0, o10 = iy0 * Ww + ix1;
        int o01 = iy1 * Ww + ix0, o11 = iy1 * Ww + ix1;

        const float* src = features + (size_t)((i + 1) * Bsz + b) * Cn * HWp;
        float wv8 = wvw * 0.125f;
        #pragma unroll
        for (int c = 0; c < Cn; ++c) {
            const float* sc = src + (size_t)c * HWp;
            float v = w00 * sc[o00] + w10 * sc[o10] + w01 * sc[o01] + w11 * sc[o11];
            acc[c >> 3] += v * ref[c] * wv8;
        }
    }

    float invvw = 1.0f / vw_sum;
    size_t outbase = (size_t)b * Gg * Dd * HWp;
    #pragma unroll
    for (int g = 0; g < Gg; ++g)
        out[outbase + (size_t)(g * Dd + d) * HWp + p] = acc[g] * invvw;
    // samples output, appended after cor_feats
    out[(size_t)Bsz * Gg * Dd * HWp + (size_t)(b * Dd + d) * HWp + p] = sample;
}

extern "C" void kernel_launch(void* const* d_in, const int* in_sizes, int n_in,
                              void* d_out, int out_size, void* d_ws, size_t ws_size,
                              hipStream_t stream) {
    const float* inv_depth = (const float*)d_in[0];
    const float* features  = (const float*)d_in[1];
    const float* pm        = (const float*)d_in[2];
    const float* vw        = (const float*)d_in[3];
    const float* conf      = (const float*)d_in[4];
    const float* dI        = (const float*)d_in[5];
    const float* dmax      = (const float*)d_in[6];
    const float* dmin      = (const float*)d_in[7];
    float* RT = (float*)d_ws;

    hipLaunchKernelGGL(setup_rt, dim3(1), dim3(64), 0, stream, pm, RT);

    int total = Bsz * Dd * HWp;
    hipLaunchKernelGGL(getcost_main, dim3((total + 255) / 256), dim3(256), 0, stream,
                       inv_depth, features, vw, conf, dI, dmax, dmin, RT, (float*)d_out);
}

// Round 2
// 171.944 us; speedup vs baseline: 1.3516x; 1.3516x over previous
//
#include <hip/hip_runtime.h>

// Problem constants (fixed by harness setup_inputs):
// B=2, V=5, C=32, H=256, W=320, D=CostNum=4, G=4
#define Bsz 2
#define Vn  5
#define Cn  32
#define Gg  4
#define Hh  256
#define Ww  320
#define Dd  4
#define HWp (Hh*Ww)

#define NVB ((Vn-1)*Bsz)                   // 8 (src view, batch) pairs
#define T_OFFSET 512                        // bytes; RT lives at ws[0..384)
#define T_BYTES ((size_t)NVB * HWp * Cn * sizeof(float))   // ~83.9 MB

// ---------------------------------------------------------------------------
// Setup kernel: per batch, build make_proj(P) for all views, invert ref proj,
// store rot(3x3)+trans(3) of src_proj @ inv(ref_proj) for each src view.
// ---------------------------------------------------------------------------
__global__ void setup_rt(const float* __restrict__ pm, float* __restrict__ RT) {
    int b = threadIdx.x;
    if (b >= Bsz) return;

    float P[Vn][16];
    for (int v = 0; v < Vn; ++v) {
        const float* E = pm + ((b * Vn + v) * 2 + 0) * 16;
        const float* K = pm + ((b * Vn + v) * 2 + 1) * 16;
        for (int i = 0; i < 3; ++i)
            for (int j = 0; j < 4; ++j) {
                float s = 0.f;
                for (int k = 0; k < 3; ++k) s += K[i * 4 + k] * E[k * 4 + j];
                P[v][i * 4 + j] = s;
            }
        for (int j = 0; j < 4; ++j) P[v][12 + j] = E[12 + j];
    }

    float A[4][8];
    for (int i = 0; i < 4; ++i)
        for (int j = 0; j < 4; ++j) {
            A[i][j] = P[0][i * 4 + j];
            A[i][4 + j] = (i == j) ? 1.f : 0.f;
        }
    for (int col = 0; col < 4; ++col) {
        int piv = col;
        float best = fabsf(A[col][col]);
        for (int r = col + 1; r < 4; ++r) {
            float v = fabsf(A[r][col]);
            if (v > best) { best = v; piv = r; }
        }
        if (piv != col)
            for (int j = 0; j < 8; ++j) {
                float t = A[col][j]; A[col][j] = A[piv][j]; A[piv][j] = t;
            }
        float inv = 1.f / A[col][col];
        for (int j = 0; j < 8; ++j) A[col][j] *= inv;
        for (int r = 0; r < 4; ++r)
            if (r != col) {
                float f = A[r][col];
                for (int j = 0; j < 8; ++j) A[r][j] -= f * A[col][j];
            }
    }
    float inv0[16];
    for (int i = 0; i < 4; ++i)
        for (int j = 0; j < 4; ++j) inv0[i * 4 + j] = A[i][4 + j];

    for (int i2 = 0; i2 < Vn - 1; ++i2) {
        const float* Ps = P[i2 + 1];
        float M[12];
        for (int i = 0; i < 3; ++i)
            for (int j = 0; j < 4; ++j) {
                float s = 0.f;
                for (int k = 0; k < 4; ++k) s += Ps[i * 4 + k] * inv0[k * 4 + j];
                M[i * 4 + j] = s;
            }
        float* o = RT + (b * (Vn - 1) + i2) * 12;
        o[0] = M[0];  o[1] = M[1];  o[2] = M[2];
        o[3] = M[4];  o[4] = M[5];  o[5] = M[6];
        o[6] = M[8];  o[7] = M[9];  o[8] = M[10];
        o[9] = M[3];  o[10] = M[7]; o[11] = M[11];
    }
}

// ---------------------------------------------------------------------------
// Transpose src views planar (C,HW) -> pixel-major interleaved T[vb][p][c].
// Reads coalesced (lanes consecutive in p), writes coalesced (contiguous
// 128B per thread, consecutive across lanes).
// ---------------------------------------------------------------------------
__global__ __launch_bounds__(256) void transpose_src(
    const float* __restrict__ features, float* __restrict__ T)
{
    int tid = blockIdx.x * blockDim.x + threadIdx.x;
    if (tid >= NVB * HWp) return;
    int p  = tid % HWp;
    int vb = tid / HWp;

    const float* src = features + (size_t)(vb + Bsz) * Cn * HWp + p;
    float v[Cn];
    #pragma unroll
    for (int c = 0; c < Cn; ++c) v[c] = src[(size_t)c * HWp];

    float4* dst = (float4*)(T + ((size_t)vb * HWp + p) * Cn);
    #pragma unroll
    for (int q = 0; q < Cn / 4; ++q)
        dst[q] = make_float4(v[4*q], v[4*q+1], v[4*q+2], v[4*q+3]);
}

// ---------------------------------------------------------------------------
// Main kernel (interleaved path): one thread per (b, d, pixel).
// Per view: warp coords, 4 corner gathers of 32 contiguous channels each,
// per-corner group dot, bilinear-combine the scalars.
// ---------------------------------------------------------------------------
__global__ __launch_bounds__(256, 4) void getcost_fast(
    const float* __restrict__ inv_depth,
    const float* __restrict__ features,
    const float* __restrict__ view_weights,
    const float* __restrict__ confidence,
    const float* __restrict__ sc_interval,
    const float* __restrict__ sc_dmax,
    const float* __restrict__ sc_dmin,
    const float* __restrict__ RT,
    const float* __restrict__ T,
    float* __restrict__ out)
{
    int tid = blockIdx.x * blockDim.x + threadIdx.x;
    if (tid >= Bsz * Dd * HWp) return;
    int p  = tid % HWp;
    int bd = tid / HWp;
    int d  = bd % Dd;
    int b  = bd / Dd;
    int h  = p / Ww;
    int w  = p % Ww;

    float dI    = sc_interval[0];
    float dmaxv = sc_dmax[0];
    float dminv = sc_dmin[0];

    float cur  = inv_depth[b * HWp + p];
    float conf = confidence[b * HWp + p];
    float radius0 = (float)(Dd / 2) * dI;
    float radius  = 0.2f * radius0 + (1.0f - conf) * 1.8f * radius0;
    float dmin_   = cur - radius;
    float interval = 2.0f * radius / (float)(Dd - 1);
    float sample = (float)d * interval + dmin_;
    sample = fminf(fmaxf(sample, 0.0f), 1.0f);
    float min_disp = 1.0f / dmaxv;
    float max_disp = 1.0f / dminv;
    float depth = 1.0f / fmaxf(min_disp + (max_disp - min_disp) * sample, 1e-6f);

    // ref feature channels (coalesced planar reads)
    float ref[Cn];
    const float* reff = features + (size_t)b * Cn * HWp + p;
    #pragma unroll
    for (int c = 0; c < Cn; ++c) ref[c] = reff[(size_t)c * HWp];

    float acc[Gg] = {0.f, 0.f, 0.f, 0.f};
    float vw_sum = 1e-8f;
    float xf = (float)w, yf = (float)h;

    #pragma unroll
    for (int i = 0; i < Vn - 1; ++i) {
        const float* rt = RT + (b * (Vn - 1) + i) * 12;
        float rx = rt[0] * xf + rt[1] * yf + rt[2];
        float ry = rt[3] * xf + rt[4] * yf + rt[5];
        float rz = rt[6] * xf + rt[7] * yf + rt[8];
        float wvw = view_weights[((size_t)(b * (Vn - 1) + i)) * HWp + p];
        vw_sum += wvw;

        float ptx = rx * depth + rt[9];
        float pty = ry * depth + rt[10];
        float ptz = rz * depth + rt[11];
        if (ptz == 0.0f) ptz = 1e-8f;
        float px = ptx / ptz, py = pty / ptz;

        float x0 = floorf(px), y0 = floorf(py);
        float wx = px - x0,   wy = py - y0;
        float x1 = x0 + 1.0f, y1 = y0 + 1.0f;
        bool vx0 = (x0 >= 0.f) && (x0 <= (float)(Ww - 1));
        bool vx1 = (x1 >= 0.f) && (x1 <= (float)(Ww - 1));
        bool vy0 = (y0 >= 0.f) && (y0 <= (float)(Hh - 1));
        bool vy1 = (y1 >= 0.f) && (y1 <= (float)(Hh - 1));
        int ix0 = (int)fminf(fmaxf(x0, 0.f), (float)(Ww - 1));
        int ix1 = (int)fminf(fmaxf(x1, 0.f), (float)(Ww - 1));
        int iy0 = (int)fminf(fmaxf(y0, 0.f), (float)(Hh - 1));
        int iy1 = (int)fminf(fmaxf(y1, 0.f), (float)(Hh - 1));
        float cw[4];
        cw[0] = (vx0 && vy0) ? (1.f - wx) * (1.f - wy) : 0.f;
        cw[1] = (vx1 && vy0) ? wx * (1.f - wy) : 0.f;
        cw[2] = (vx0 && vy1) ? (1.f - wx) * wy : 0.f;
        cw[3] = (vx1 && vy1) ? wx * wy : 0.f;
        int co[4];
        co[0] = iy0 * Ww + ix0; co[1] = iy0 * Ww + ix1;
        co[2] = iy1 * Ww + ix0; co[3] = iy1 * Ww + ix1;

        const float* tv = T + (size_t)(i * Bsz + b) * HWp * Cn;
        float vsum[Gg] = {0.f, 0.f, 0.f, 0.f};
        #pragma unroll
        for (int k = 0; k < 4; ++k) {
            const float4* tc = (const float4*)(tv + (size_t)co[k] * Cn);
            float cg[Gg] = {0.f, 0.f, 0.f, 0.f};
            #pragma unroll
            for (int q = 0; q < Cn / 4; ++q) {
                float4 s = tc[q];
                cg[q >> 1] += s.x * ref[4*q] + s.y * ref[4*q+1]
                            + s.z * ref[4*q+2] + s.w * ref[4*q+3];
            }
            #pragma unroll
            for (int g = 0; g < Gg; ++g) vsum[g] += cw[k] * cg[g];
        }
        float wv8 = wvw * 0.125f;
        #pragma unroll
        for (int g = 0; g < Gg; ++g) acc[g] += wv8 * vsum[g];
    }

    float invvw = 1.0f / vw_sum;
    size_t outbase = (size_t)b * Gg * Dd * HWp;
    #pragma unroll
    for (int g = 0; g < Gg; ++g)
        out[outbase + (size_t)(g * Dd + d) * HWp + p] = acc[g] * invvw;
    out[(size_t)Bsz * Gg * Dd * HWp + (size_t)(b * Dd + d) * HWp + p] = sample;
}

// ---------------------------------------------------------------------------
// Fallback kernel (verified R1 path) if ws is too small for the transpose.
// ---------------------------------------------------------------------------
__global__ __launch_bounds__(256) void getcost_main(
    const float* __restrict__ inv_depth,
    const float* __restrict__ features,
    const float* __restrict__ view_weights,
    const float* __restrict__ confidence,
    const float* __restrict__ sc_interval,
    const float* __restrict__ sc_dmax,
    const float* __restrict__ sc_dmin,
    const float* __restrict__ RT,
    float* __restrict__ out)
{
    int tid = blockIdx.x * blockDim.x + threadIdx.x;
    if (tid >= Bsz * Dd * HWp) return;
    int p  = tid % HWp;
    int bd = tid / HWp;
    int d  = bd % Dd;
    int b  = bd / Dd;
    int h  = p / Ww;
    int w  = p % Ww;

    float dI    = sc_interval[0];
    float dmaxv = sc_dmax[0];
    float dminv = sc_dmin[0];

    float cur  = inv_depth[b * HWp + p];
    float conf = confidence[b * HWp + p];
    float radius0 = (float)(Dd / 2) * dI;
    float radius  = 0.2f * radius0 + (1.0f - conf) * 1.8f * radius0;
    float dmin_   = cur - radius;
    float interval = 2.0f * radius / (float)(Dd - 1);
    float sample = (float)d * interval + dmin_;
    sample = fminf(fmaxf(sample, 0.0f), 1.0f);
    float min_disp = 1.0f / dmaxv;
    float max_disp = 1.0f / dminv;
    float depth = 1.0f / fmaxf(min_disp + (max_disp - min_disp) * sample, 1e-6f);

    float ref[Cn];
    const float* reff = features + (size_t)b * Cn * HWp + p;
    #pragma unroll
    for (int c = 0; c < Cn; ++c) ref[c] = reff[(size_t)c * HWp];

    float acc[Gg] = {0.f, 0.f, 0.f, 0.f};
    float vw_sum = 1e-8f;
    float xf = (float)w, yf = (float)h;

    #pragma unroll
    for (int i = 0; i < Vn - 1; ++i) {
        const float* rt = RT + (b * (Vn - 1) + i) * 12;
        float rx = rt[0] * xf + rt[1] * yf + rt[2];
        float ry = rt[3] * xf + rt[4] * yf + rt[5];
        float rz = rt[6] * xf + rt[7] * yf + rt[8];
        float wvw = view_weights[((size_t)(b * (Vn - 1) + i)) * HWp + p];
        vw_sum += wvw;

        float ptx = rx * depth + rt[9];
        float pty = ry * depth + rt[10];
        float ptz = rz * depth + rt[11];
        if (ptz == 0.0f) ptz = 1e-8f;
        float px = ptx / ptz, py = pty / ptz;

        float x0 = floorf(px), y0 = floorf(py);
        float wx = px - x0,   wy = py - y0;
        float x1 = x0 + 1.0f, y1 = y0 + 1.0f;
        bool vx0 = (x0 >= 0.f) && (x0 <= (float)(Ww - 1));
        bool vx1 = (x1 >= 0.f) && (x1 <= (float)(Ww - 1));
        bool vy0 = (y0 >= 0.f) && (y0 <= (float)(Hh - 1));
        bool vy1 = (y1 >= 0.f) && (y1 <= (float)(Hh - 1));
        int ix0 = (int)fminf(fmaxf(x0, 0.f), (float)(Ww - 1));
        int ix1 = (int)fminf(fmaxf(x1, 0.f), (float)(Ww - 1));
        int iy0 = (int)fminf(fmaxf(y0, 0.f), (float)(Hh - 1));
        int iy1 = (int)fminf(fmaxf(y1, 0.f), (float)(Hh - 1));
        float w00 = (vx0 && vy0) ? (1.f - wx) * (1.f - wy) : 0.f;
        float w10 = (vx1 && vy0) ? wx * (1.f - wy) : 0.f;
        float w01 = (vx0 && vy1) ? (1.f - wx) * wy : 0.f;
        float w11 = (vx1 && vy1) ? wx * wy : 0.f;
        int o00 = iy0 * Ww + ix0, o10 = iy0 * Ww + ix1;
        int o01 = iy1 * Ww + ix0, o11 = iy1 * Ww + ix1;

        const float* src = features + (size_t)((i + 1) * Bsz + b) * Cn * HWp;
        float wv8 = wvw * 0.125f;
        #pragma unroll
        for (int c = 0; c < Cn; ++c) {
            const float* sc = src + (size_t)c * HWp;
            float v = w00 * sc[o00] + w10 * sc[o10] + w01 * sc[o01] + w11 * sc[o11];
            acc[c >> 3] += v * ref[c] * wv8;
        }
    }

    float invvw = 1.0f / vw_sum;
    size_t outbase = (size_t)b * Gg * Dd * HWp;
    #pragma unroll
    for (int g = 0; g < Gg; ++g)
        out[outbase + (size_t)(g * Dd + d) * HWp + p] = acc[g] * invvw;
    out[(size_t)Bsz * Gg * Dd * HWp + (size_t)(b * Dd + d) * HWp + p] = sample;
}

extern "C" void kernel_launch(void* const* d_in, const int* in_sizes, int n_in,
                              void* d_out, int out_size, void* d_ws, size_t ws_size,
                              hipStream_t stream) {
    const float* inv_depth = (const float*)d_in[0];
    const float* features  = (const float*)d_in[1];
    const float* pm        = (const float*)d_in[2];
    const float* vw        = (const float*)d_in[3];
    const float* conf      = (const float*)d_in[4];
    const float* dI        = (const float*)d_in[5];
    const float* dmax      = (const float*)d_in[6];
    const float* dmin      = (const float*)d_in[7];
    float* RT = (float*)d_ws;

    hipLaunchKernelGGL(setup_rt, dim3(1), dim3(64), 0, stream, pm, RT);

    int total = Bsz * Dd * HWp;
    bool has_ws = (ws_size >= T_OFFSET + T_BYTES);

    if (has_ws) {
        float* T = (float*)((char*)d_ws + T_OFFSET);
        int ttot = NVB * HWp;
        hipLaunchKernelGGL(transpose_src, dim3((ttot + 255) / 256), dim3(256), 0, stream,
                           features, T);
        hipLaunchKernelGGL(getcost_fast, dim3((total + 255) / 256), dim3(256), 0, stream,
                           inv_depth, features, vw, conf, dI, dmax, dmin, RT, T,
                           (float*)d_out);
    } else {
        hipLaunchKernelGGL(getcost_main, dim3((total + 255) / 256), dim3(256), 0, stream,
                           inv_depth, features, vw, conf, dI, dmax, dmin, RT,
                           (float*)d_out);
    }
}

// Round 3
// 107.159 us; speedup vs baseline: 2.1687x; 1.6046x over previous
//
#include <hip/hip_runtime.h>

// Problem constants (fixed by harness setup_inputs):
// B=2, V=5, C=32, H=256, W=320, D=CostNum=4, G=4
#define Bsz 2
#define Vn  5
#define Cn  32
#define Gg  4
#define Hh  256
#define Ww  320
#define Dd  4
#define HWp (Hh*Ww)

#define NVB ((Vn-1)*Bsz)                    // 8 (src view, batch) pairs
#define T_OFFSET 512                        // bytes; RT lives at ws[0..384)
// bf16-packed: 32 channels -> 16 uint32 (64 B) per pixel
#define T_BYTES ((size_t)NVB * HWp * (Cn/2) * sizeof(unsigned int))   // ~41.9 MB

__device__ __forceinline__ unsigned int f2bf_rne(float x) {
    unsigned int u = __float_as_uint(x);
    return (u + 0x7fffu + ((u >> 16) & 1u)) >> 16;
}

// ---------------------------------------------------------------------------
// Setup kernel: per batch, build make_proj(P) for all views, invert ref proj,
// store rot(3x3)+trans(3) of src_proj @ inv(ref_proj) for each src view.
// ---------------------------------------------------------------------------
__global__ void setup_rt(const float* __restrict__ pm, float* __restrict__ RT) {
    int b = threadIdx.x;
    if (b >= Bsz) return;

    float P[Vn][16];
    for (int v = 0; v < Vn; ++v) {
        const float* E = pm + ((b * Vn + v) * 2 + 0) * 16;
        const float* K = pm + ((b * Vn + v) * 2 + 1) * 16;
        for (int i = 0; i < 3; ++i)
            for (int j = 0; j < 4; ++j) {
                float s = 0.f;
                for (int k = 0; k < 3; ++k) s += K[i * 4 + k] * E[k * 4 + j];
                P[v][i * 4 + j] = s;
            }
        for (int j = 0; j < 4; ++j) P[v][12 + j] = E[12 + j];
    }

    float A[4][8];
    for (int i = 0; i < 4; ++i)
        for (int j = 0; j < 4; ++j) {
            A[i][j] = P[0][i * 4 + j];
            A[i][4 + j] = (i == j) ? 1.f : 0.f;
        }
    for (int col = 0; col < 4; ++col) {
        int piv = col;
        float best = fabsf(A[col][col]);
        for (int r = col + 1; r < 4; ++r) {
            float v = fabsf(A[r][col]);
            if (v > best) { best = v; piv = r; }
        }
        if (piv != col)
            for (int j = 0; j < 8; ++j) {
                float t = A[col][j]; A[col][j] = A[piv][j]; A[piv][j] = t;
            }
        float inv = 1.f / A[col][col];
        for (int j = 0; j < 8; ++j) A[col][j] *= inv;
        for (int r = 0; r < 4; ++r)
            if (r != col) {
                float f = A[r][col];
                for (int j = 0; j < 8; ++j) A[r][j] -= f * A[col][j];
            }
    }
    float inv0[16];
    for (int i = 0; i < 4; ++i)
        for (int j = 0; j < 4; ++j) inv0[i * 4 + j] = A[i][4 + j];

    for (int i2 = 0; i2 < Vn - 1; ++i2) {
        const float* Ps = P[i2 + 1];
        float M[12];
        for (int i = 0; i < 3; ++i)
            for (int j = 0; j < 4; ++j) {
                float s = 0.f;
                for (int k = 0; k < 4; ++k) s += Ps[i * 4 + k] * inv0[k * 4 + j];
                M[i * 4 + j] = s;
            }
        float* o = RT + (b * (Vn - 1) + i2) * 12;
        o[0] = M[0];  o[1] = M[1];  o[2] = M[2];
        o[3] = M[4];  o[4] = M[5];  o[5] = M[6];
        o[6] = M[8];  o[7] = M[9];  o[8] = M[10];
        o[9] = M[3];  o[10] = M[7]; o[11] = M[11];
    }
}

// ---------------------------------------------------------------------------
// Transpose src views planar (C,HW) -> pixel-major bf16-packed T[vb][p][c/2].
// Reads coalesced planar fp32, writes 64B contiguous per thread.
// ---------------------------------------------------------------------------
__global__ __launch_bounds__(256) void transpose_src_bf16(
    const float* __restrict__ features, unsigned int* __restrict__ T)
{
    int tid = blockIdx.x * blockDim.x + threadIdx.x;
    if (tid >= NVB * HWp) return;
    int p  = tid % HWp;
    int vb = tid / HWp;

    const float* src = features + (size_t)(vb + Bsz) * Cn * HWp + p;
    float v[Cn];
    #pragma unroll
    for (int c = 0; c < Cn; ++c) v[c] = src[(size_t)c * HWp];

    uint4* dst = (uint4*)(T + ((size_t)vb * HWp + p) * (Cn / 2));
    #pragma unroll
    for (int q = 0; q < Cn / 8; ++q) {
        uint4 o;
        o.x = f2bf_rne(v[8*q + 0]) | (f2bf_rne(v[8*q + 1]) << 16);
        o.y = f2bf_rne(v[8*q + 2]) | (f2bf_rne(v[8*q + 3]) << 16);
        o.z = f2bf_rne(v[8*q + 4]) | (f2bf_rne(v[8*q + 5]) << 16);
        o.w = f2bf_rne(v[8*q + 6]) | (f2bf_rne(v[8*q + 7]) << 16);
        dst[q] = o;
    }
}

// ---------------------------------------------------------------------------
// Main kernel: one thread per (b, d, pixel). Per view: warp coords, 4 corner
// gathers of 4x uint4 (64B, 32 bf16 channels), per-corner group dot in fp32,
// bilinear-combine the 4 scalars per group.
// ---------------------------------------------------------------------------
__global__ __launch_bounds__(256, 4) void getcost_fast(
    const float* __restrict__ inv_depth,
    const float* __restrict__ features,
    const float* __restrict__ view_weights,
    const float* __restrict__ confidence,
    const float* __restrict__ sc_interval,
    const float* __restrict__ sc_dmax,
    const float* __restrict__ sc_dmin,
    const float* __restrict__ RT,
    const unsigned int* __restrict__ T,
    float* __restrict__ out)
{
    int tid = blockIdx.x * blockDim.x + threadIdx.x;
    if (tid >= Bsz * Dd * HWp) return;
    int p  = tid % HWp;
    int bd = tid / HWp;
    int d  = bd % Dd;
    int b  = bd / Dd;
    int h  = p / Ww;
    int w  = p % Ww;

    float dI    = sc_interval[0];
    float dmaxv = sc_dmax[0];
    float dminv = sc_dmin[0];

    float cur  = inv_depth[b * HWp + p];
    float conf = confidence[b * HWp + p];
    float radius0 = (float)(Dd / 2) * dI;
    float radius  = 0.2f * radius0 + (1.0f - conf) * 1.8f * radius0;
    float dmin_   = cur - radius;
    float interval = 2.0f * radius / (float)(Dd - 1);
    float sample = (float)d * interval + dmin_;
    sample = fminf(fmaxf(sample, 0.0f), 1.0f);
    float min_disp = 1.0f / dmaxv;
    float max_disp = 1.0f / dminv;
    float depth = 1.0f / fmaxf(min_disp + (max_disp - min_disp) * sample, 1e-6f);

    // ref feature channels (coalesced planar reads, fp32 exact)
    float ref[Cn];
    const float* reff = features + (size_t)b * Cn * HWp + p;
    #pragma unroll
    for (int c = 0; c < Cn; ++c) ref[c] = reff[(size_t)c * HWp];

    float acc[Gg] = {0.f, 0.f, 0.f, 0.f};
    float vw_sum = 1e-8f;
    float xf = (float)w, yf = (float)h;

    #pragma unroll
    for (int i = 0; i < Vn - 1; ++i) {
        const float* rt = RT + (b * (Vn - 1) + i) * 12;
        float rx = rt[0] * xf + rt[1] * yf + rt[2];
        float ry = rt[3] * xf + rt[4] * yf + rt[5];
        float rz = rt[6] * xf + rt[7] * yf + rt[8];
        float wvw = view_weights[((size_t)(b * (Vn - 1) + i)) * HWp + p];
        vw_sum += wvw;

        float ptx = rx * depth + rt[9];
        float pty = ry * depth + rt[10];
        float ptz = rz * depth + rt[11];
        if (ptz == 0.0f) ptz = 1e-8f;
        float px = ptx / ptz, py = pty / ptz;

        float x0 = floorf(px), y0 = floorf(py);
        float wx = px - x0,   wy = py - y0;
        float x1 = x0 + 1.0f, y1 = y0 + 1.0f;
        bool vx0 = (x0 >= 0.f) && (x0 <= (float)(Ww - 1));
        bool vx1 = (x1 >= 0.f) && (x1 <= (float)(Ww - 1));
        bool vy0 = (y0 >= 0.f) && (y0 <= (float)(Hh - 1));
        bool vy1 = (y1 >= 0.f) && (y1 <= (float)(Hh - 1));
        int ix0 = (int)fminf(fmaxf(x0, 0.f), (float)(Ww - 1));
        int ix1 = (int)fminf(fmaxf(x1, 0.f), (float)(Ww - 1));
        int iy0 = (int)fminf(fmaxf(y0, 0.f), (float)(Hh - 1));
        int iy1 = (int)fminf(fmaxf(y1, 0.f), (float)(Hh - 1));
        float cw[4];
        cw[0] = (vx0 && vy0) ? (1.f - wx) * (1.f - wy) : 0.f;
        cw[1] = (vx1 && vy0) ? wx * (1.f - wy) : 0.f;
        cw[2] = (vx0 && vy1) ? (1.f - wx) * wy : 0.f;
        cw[3] = (vx1 && vy1) ? wx * wy : 0.f;
        int co[4];
        co[0] = iy0 * Ww + ix0; co[1] = iy0 * Ww + ix1;
        co[2] = iy1 * Ww + ix0; co[3] = iy1 * Ww + ix1;

        const unsigned int* tv = T + (size_t)(i * Bsz + b) * HWp * (Cn / 2);
        float vsum[Gg] = {0.f, 0.f, 0.f, 0.f};
        #pragma unroll
        for (int k = 0; k < 4; ++k) {
            const uint4* tc = (const uint4*)(tv + (size_t)co[k] * (Cn / 2));
            #pragma unroll
            for (int g = 0; g < Gg; ++g) {          // one uint4 == one group (8 ch)
                uint4 u = tc[g];
                float dot =
                    __uint_as_float(u.x << 16)          * ref[8*g + 0]
                  + __uint_as_float(u.x & 0xffff0000u)  * ref[8*g + 1]
                  + __uint_as_float(u.y << 16)          * ref[8*g + 2]
                  + __uint_as_float(u.y & 0xffff0000u)  * ref[8*g + 3]
                  + __uint_as_float(u.z << 16)          * ref[8*g + 4]
                  + __uint_as_float(u.z & 0xffff0000u)  * ref[8*g + 5]
                  + __uint_as_float(u.w << 16)          * ref[8*g + 6]
                  + __uint_as_float(u.w & 0xffff0000u)  * ref[8*g + 7];
                vsum[g] += cw[k] * dot;
            }
        }
        float wv8 = wvw * 0.125f;
        #pragma unroll
        for (int g = 0; g < Gg; ++g) acc[g] += wv8 * vsum[g];
    }

    float invvw = 1.0f / vw_sum;
    size_t outbase = (size_t)b * Gg * Dd * HWp;
    #pragma unroll
    for (int g = 0; g < Gg; ++g)
        out[outbase + (size_t)(g * Dd + d) * HWp + p] = acc[g] * invvw;
    out[(size_t)Bsz * Gg * Dd * HWp + (size_t)(b * Dd + d) * HWp + p] = sample;
}

// ---------------------------------------------------------------------------
// Fallback kernel (verified R1 path) if ws is too small for the transpose.
// ---------------------------------------------------------------------------
__global__ __launch_bounds__(256) void getcost_main(
    const float* __restrict__ inv_depth,
    const float* __restrict__ features,
    const float* __restrict__ view_weights,
    const float* __restrict__ confidence,
    const float* __restrict__ sc_interval,
    const float* __restrict__ sc_dmax,
    const float* __restrict__ sc_dmin,
    const float* __restrict__ RT,
    float* __restrict__ out)
{
    int tid = blockIdx.x * blockDim.x + threadIdx.x;
    if (tid >= Bsz * Dd * HWp) return;
    int p  = tid % HWp;
    int bd = tid / HWp;
    int d  = bd % Dd;
    int b  = bd / Dd;
    int h  = p / Ww;
    int w  = p % Ww;

    float dI    = sc_interval[0];
    float dmaxv = sc_dmax[0];
    float dminv = sc_dmin[0];

    float cur  = inv_depth[b * HWp + p];
    float conf = confidence[b * HWp + p];
    float radius0 = (float)(Dd / 2) * dI;
    float radius  = 0.2f * radius0 + (1.0f - conf) * 1.8f * radius0;
    float dmin_   = cur - radius;
    float interval = 2.0f * radius / (float)(Dd - 1);
    float sample = (float)d * interval + dmin_;
    sample = fminf(fmaxf(sample, 0.0f), 1.0f);
    float min_disp = 1.0f / dmaxv;
    float max_disp = 1.0f / dminv;
    float depth = 1.0f / fmaxf(min_disp + (max_disp - min_disp) * sample, 1e-6f);

    float ref[Cn];
    const float* reff = features + (size_t)b * Cn * HWp + p;
    #pragma unroll
    for (int c = 0; c < Cn; ++c) ref[c] = reff[(size_t)c * HWp];

    float acc[Gg] = {0.f, 0.f, 0.f, 0.f};
    float vw_sum = 1e-8f;
    float xf = (float)w, yf = (float)h;

    #pragma unroll
    for (int i = 0; i < Vn - 1; ++i) {
        const float* rt = RT + (b * (Vn - 1) + i) * 12;
        float rx = rt[0] * xf + rt[1] * yf + rt[2];
        float ry = rt[3] * xf + rt[4] * yf + rt[5];
        float rz = rt[6] * xf + rt[7] * yf + rt[8];
        float wvw = view_weights[((size_t)(b * (Vn - 1) + i)) * HWp + p];
        vw_sum += wvw;

        float ptx = rx * depth + rt[9];
        float pty = ry * depth + rt[10];
        float ptz = rz * depth + rt[11];
        if (ptz == 0.0f) ptz = 1e-8f;
        float px = ptx / ptz, py = pty / ptz;

        float x0 = floorf(px), y0 = floorf(py);
        float wx = px - x0,   wy = py - y0;
        float x1 = x0 + 1.0f, y1 = y0 + 1.0f;
        bool vx0 = (x0 >= 0.f) && (x0 <= (float)(Ww - 1));
        bool vx1 = (x1 >= 0.f) && (x1 <= (float)(Ww - 1));
        bool vy0 = (y0 >= 0.f) && (y0 <= (float)(Hh - 1));
        bool vy1 = (y1 >= 0.f) && (y1 <= (float)(Hh - 1));
        int ix0 = (int)fminf(fmaxf(x0, 0.f), (float)(Ww - 1));
        int ix1 = (int)fminf(fmaxf(x1, 0.f), (float)(Ww - 1));
        int iy0 = (int)fminf(fmaxf(y0, 0.f), (float)(Hh - 1));
        int iy1 = (int)fminf(fmaxf(y1, 0.f), (float)(Hh - 1));
        float w00 = (vx0 && vy0) ? (1.f - wx) * (1.f - wy) : 0.f;
        float w10 = (vx1 && vy0) ? wx * (1.f - wy) : 0.f;
        float w01 = (vx0 && vy1) ? (1.f - wx) * wy : 0.f;
        float w11 = (vx1 && vy1) ? wx * wy : 0.f;
        int o00 = iy0 * Ww + ix0, o10 = iy0 * Ww + ix1;
        int o01 = iy1 * Ww + ix0, o11 = iy1 * Ww + ix1;

        const float* src = features + (size_t)((i + 1) * Bsz + b) * Cn * HWp;
        float wv8 = wvw * 0.125f;
        #pragma unroll
        for (int c = 0; c < Cn; ++c) {
            const float* sc = src + (size_t)c * HWp;
            float v = w00 * sc[o00] + w10 * sc[o10] + w01 * sc[o01] + w11 * sc[o11];
            acc[c >> 3] += v * ref[c] * wv8;
        }
    }

    float invvw = 1.0f / vw_sum;
    size_t outbase = (size_t)b * Gg * Dd * HWp;
    #pragma unroll
    for (int g = 0; g < Gg; ++g)
        out[outbase + (size_t)(g * Dd + d) * HWp + p] = acc[g] * invvw;
    out[(size_t)Bsz * Gg * Dd * HWp + (size_t)(b * Dd + d) * HWp + p] = sample;
}

extern "C" void kernel_launch(void* const* d_in, const int* in_sizes, int n_in,
                              void* d_out, int out_size, void* d_ws, size_t ws_size,
                              hipStream_t stream) {
    const float* inv_depth = (const float*)d_in[0];
    const float* features  = (const float*)d_in[1];
    const float* pm        = (const float*)d_in[2];
    const float* vw        = (const float*)d_in[3];
    const float* conf      = (const float*)d_in[4];
    const float* dI        = (const float*)d_in[5];
    const float* dmax      = (const float*)d_in[6];
    const float* dmin      = (const float*)d_in[7];
    float* RT = (float*)d_ws;

    hipLaunchKernelGGL(setup_rt, dim3(1), dim3(64), 0, stream, pm, RT);

    int total = Bsz * Dd * HWp;
    bool has_ws = (ws_size >= T_OFFSET + T_BYTES);

    if (has_ws) {
        unsigned int* T = (unsigned int*)((char*)d_ws + T_OFFSET);
        int ttot = NVB * HWp;
        hipLaunchKernelGGL(transpose_src_bf16, dim3((ttot + 255) / 256), dim3(256), 0,
                           stream, features, T);
        hipLaunchKernelGGL(getcost_fast, dim3((total + 255) / 256), dim3(256), 0, stream,
                           inv_depth, features, vw, conf, dI, dmax, dmin, RT, T,
                           (float*)d_out);
    } else {
        hipLaunchKernelGGL(getcost_main, dim3((total + 255) / 256), dim3(256), 0, stream,
                           inv_depth, features, vw, conf, dI, dmax, dmin, RT,
                           (float*)d_out);
    }
}